// Round 13
// baseline (164.254 us; speedup 1.0000x reference)
//
#include <hip/hip_runtime.h>
#include <hip/hip_fp16.h>

// ---------------------------------------------------------------------------
// Round-13: r10 skeleton (proven 110us), prep chain slimmed.
//   memset(counts+earr, one region) ;
//   convhist (fp32->fp16 table conv + 391-bucket hist + efeat column
//             accumulated into dense earr[N] via global fp32 atomics) ;
//   scan (1 block: bucket offsets, also writes noff[N]=E) ;
//   bin (4B keys, 256-node buckets -> ~42B flush runs, 28KB LDS) ;
//   bsort (bucket-local counting sort over the window: node-sorted 4B src
//          array + per-node offsets; no efeat work) ;
//   gather (r10-proven: 1 wave/node, 8-deep unroll, fp16 rows, linear store;
//           lane0 writes out[:,64] = earr[wid]).
// Key: (dst & 255) << 17 | src   (needs N <= 2^17).
// ---------------------------------------------------------------------------

#define NB_SHIFT 8
#define BNODES   256          // nodes per bucket
#define SRC_BITS 17
#define SRC_MASK ((1 << SRC_BITS) - 1)
#define BIN_S    4096         // edges per bin/hist block
#define BIN_T    512
#define MAXNB    512

// Fused: blocks [0, c_blocks) convert the table fp32->fp16; the rest
// histogram dst into bucket counts and accumulate efeat into earr.
__global__ __launch_bounds__(BIN_T) void convhist_kernel(const float* __restrict__ g,
                                                         __half* __restrict__ h,
                                                         int n_emb, int c_blocks,
                                                         const int* __restrict__ dst,
                                                         const float* __restrict__ ef,
                                                         int* __restrict__ counts,
                                                         float* __restrict__ earr,
                                                         int E, int NB) {
    __shared__ int cnt[MAXNB];
    int t = threadIdx.x;

    if (blockIdx.x < c_blocks) {
        int i = (blockIdx.x * BIN_T + t) * 8;
        if (i + 7 < n_emb) {
            float4 a = *(const float4*)(g + i);
            float4 b = *(const float4*)(g + i + 4);
            __half2 h0 = __floats2half2_rn(a.x, a.y);
            __half2 h1 = __floats2half2_rn(a.z, a.w);
            __half2 h2 = __floats2half2_rn(b.x, b.y);
            __half2 h3 = __floats2half2_rn(b.z, b.w);
            int4 o;
            o.x = *(int*)&h0; o.y = *(int*)&h1; o.z = *(int*)&h2; o.w = *(int*)&h3;
            *(int4*)(h + i) = o;
        } else {
            for (int k = i; k < n_emb; ++k) h[k] = __float2half(g[k]);
        }
        return;
    }

    int hb = blockIdx.x - c_blocks;
    if (t < MAXNB) cnt[t] = 0;
    __syncthreads();
    int e0 = hb * BIN_S + t * 8;
    if (e0 + 7 < E) {
        int4 a = *(const int4*)(dst + e0);
        int4 b = *(const int4*)(dst + e0 + 4);
        float4 fa = *(const float4*)(ef + e0);
        float4 fb = *(const float4*)(ef + e0 + 4);
        atomicAdd(&cnt[a.x >> NB_SHIFT], 1);  atomicAdd(&earr[a.x], fa.x);
        atomicAdd(&cnt[a.y >> NB_SHIFT], 1);  atomicAdd(&earr[a.y], fa.y);
        atomicAdd(&cnt[a.z >> NB_SHIFT], 1);  atomicAdd(&earr[a.z], fa.z);
        atomicAdd(&cnt[a.w >> NB_SHIFT], 1);  atomicAdd(&earr[a.w], fa.w);
        atomicAdd(&cnt[b.x >> NB_SHIFT], 1);  atomicAdd(&earr[b.x], fb.x);
        atomicAdd(&cnt[b.y >> NB_SHIFT], 1);  atomicAdd(&earr[b.y], fb.y);
        atomicAdd(&cnt[b.z >> NB_SHIFT], 1);  atomicAdd(&earr[b.z], fb.z);
        atomicAdd(&cnt[b.w >> NB_SHIFT], 1);  atomicAdd(&earr[b.w], fb.w);
    } else {
        for (int k = e0; k < E; ++k) {
            int d = dst[k];
            atomicAdd(&cnt[d >> NB_SHIFT], 1);
            atomicAdd(&earr[d], ef[k]);
        }
    }
    __syncthreads();
    if (t < NB && cnt[t]) atomicAdd(&counts[t], cnt[t]);
}

// Exclusive scan over NB (<=512) counters; one block, 512 threads, 1/thread.
// Also writes goff[NB]=E and noff[N]=E.
__global__ __launch_bounds__(512) void scan_kernel(const int* __restrict__ counts,
                                                   int* __restrict__ goff,
                                                   int* __restrict__ gcur,
                                                   int* __restrict__ noff,
                                                   int NB, int N) {
    __shared__ int wsum[8];
    __shared__ int wbase[8];
    int t    = threadIdx.x;
    int lane = t & 63;
    int wv   = t >> 6;
    int v    = (t < NB) ? counts[t] : 0;
    int incl = v;
#pragma unroll
    for (int o = 1; o < 64; o <<= 1) {
        int u = __shfl_up(incl, o);
        if (lane >= o) incl += u;
    }
    if (lane == 63) wsum[wv] = incl;
    __syncthreads();
    if (t < 8) {
        int s = wsum[t];
        int inc = s;
#pragma unroll
        for (int o = 1; o < 8; o <<= 1) {
            int u = __shfl_up(inc, o);
            if (t >= o) inc += u;
        }
        wbase[t] = inc - s;
    }
    __syncthreads();
    int ex = wbase[wv] + (incl - v);
    if (t < NB) { goff[t] = ex; gcur[t] = ex; }
    if (t == 511) {
        int total = wbase[7] + incl;   // padded zeros above NB
        goff[NB] = total;
        noff[N]  = total;
    }
}

// bin: local histogram+rank over 512 bucket counters (1/thread), shfl scans,
// stage 4B keys, coalesced flush into bucket runs (~42B each).
__global__ __launch_bounds__(BIN_T) void bin_kernel(const int* __restrict__ src,
                                                    const int* __restrict__ dst,
                                                    int* __restrict__ gcur,
                                                    int* __restrict__ gkey, int E) {
    __shared__ int cnt[MAXNB];              // 2 KB
    __shared__ int lbase[MAXNB];            // 2 KB
    __shared__ int wsum[8];
    __shared__ int wbase[8];
    __shared__ int skey[BIN_S];             // 16 KB
    __shared__ unsigned short sbuck[BIN_S]; // 8 KB   (total ~28 KB)

    const int t    = threadIdx.x;
    const int lane = t & 63;
    const int wv   = t >> 6;

    cnt[t] = 0;
    __syncthreads();

    int e0 = blockIdx.x * BIN_S + t * 8;
    int dv[8], sv[8], bk[8], rk[8];

    if (e0 + 7 < E) {
        *(int4*)&dv[0] = *(const int4*)(dst + e0);
        *(int4*)&dv[4] = *(const int4*)(dst + e0 + 4);
        *(int4*)&sv[0] = *(const int4*)(src + e0);
        *(int4*)&sv[4] = *(const int4*)(src + e0 + 4);
#pragma unroll
        for (int k = 0; k < 8; ++k) {
            bk[k] = dv[k] >> NB_SHIFT;
            rk[k] = atomicAdd(&cnt[bk[k]], 1);
        }
    } else {
#pragma unroll
        for (int k = 0; k < 8; ++k) {
            if (e0 + k < E) {
                dv[k] = dst[e0 + k];
                sv[k] = src[e0 + k];
                bk[k] = dv[k] >> NB_SHIFT;
                rk[k] = atomicAdd(&cnt[bk[k]], 1);
            } else {
                bk[k] = -1;
            }
        }
    }
    __syncthreads();

    // exclusive scan of cnt[0..511], 1/thread: wave shfl scan + cross-wave
    int c = cnt[t];
    int incl = c;
#pragma unroll
    for (int o = 1; o < 64; o <<= 1) {
        int u = __shfl_up(incl, o);
        if (lane >= o) incl += u;
    }
    if (lane == 63) wsum[wv] = incl;
    __syncthreads();
    if (t < 8) {
        int s = wsum[t];
        int inc = s;
#pragma unroll
        for (int o = 1; o < 8; o <<= 1) {
            int u = __shfl_up(inc, o);
            if (t >= o) inc += u;
        }
        wbase[t] = inc - s;
    }
    __syncthreads();
    int lb = wbase[wv] + (incl - c);
    lbase[t] = lb;
    __syncthreads();

    // stage ranked keys
#pragma unroll
    for (int k = 0; k < 8; ++k) {
        if (bk[k] >= 0) {
            int pos = lbase[bk[k]] + rk[k];
            skey[pos]  = ((dv[k] & (BNODES - 1)) << SRC_BITS) | sv[k];
            sbuck[pos] = (unsigned short)bk[k];
        }
    }
    // reserve; cnt[b] becomes (global_base - local_base)
    cnt[t] = (c ? atomicAdd(&gcur[t], c) : 0) - lb;
    __syncthreads();

    // coalesced flush
    int s_total = min(BIN_S, E - blockIdx.x * BIN_S);
    for (int i = t; i < s_total; i += BIN_T) {
        gkey[cnt[sbuck[i]] + i] = skey[i];
    }
}

// Bucket-local counting sort: one block per 256-node bucket, two passes over
// the window (L2-resident). Emits node-sorted 4B src array + per-node offsets.
__global__ __launch_bounds__(512) void bsort_kernel(const int* __restrict__ gkey,
                                                    const int* __restrict__ goff,
                                                    int* __restrict__ gsrc2,
                                                    int* __restrict__ noff,
                                                    int N) {
    __shared__ int cnt[BNODES];
    __shared__ int cur[BNODES];

    const int t  = threadIdx.x;
    const int b  = blockIdx.x;
    const int lo = goff[b];
    const int hi = goff[b + 1];

    if (t < BNODES) cnt[t] = 0;
    __syncthreads();

    // pass 1: per-node histogram
    for (int i = lo + t; i < hi; i += 512)
        atomicAdd(&cnt[gkey[i] >> SRC_BITS], 1);
    __syncthreads();

    // wave-0 shfl exclusive scan of 256 counters (4/lane)
    if (t < 64) {
        int c0 = cnt[4 * t], c1 = cnt[4 * t + 1], c2 = cnt[4 * t + 2], c3 = cnt[4 * t + 3];
        int ts = c0 + c1 + c2 + c3;
        int inc = ts;
#pragma unroll
        for (int o = 1; o < 64; o <<= 1) {
            int u = __shfl_up(inc, o);
            if (t >= o) inc += u;
        }
        int ex = inc - ts;
        int b0 = lo + ex;
        int b1 = b0 + c0;
        int b2 = b1 + c1;
        int b3 = b2 + c2;
        cur[4 * t]     = b0;
        cur[4 * t + 1] = b1;
        cur[4 * t + 2] = b2;
        cur[4 * t + 3] = b3;
        int node = b * BNODES + 4 * t;
        if (node     < N) noff[node]     = b0;
        if (node + 1 < N) noff[node + 1] = b1;
        if (node + 2 < N) noff[node + 2] = b2;
        if (node + 3 < N) noff[node + 3] = b3;
    }
    __syncthreads();

    // pass 2: place node-sorted srcs
    for (int i = lo + t; i < hi; i += 512) {
        int k = gkey[i];
        int pos = atomicAdd(&cur[k >> SRC_BITS], 1);
        gsrc2[pos] = k & SRC_MASK;
    }
}

// Gather: one wave per node, lane = feature, fp16 rows, 8-way unroll.
// lane0 writes the efeat column from earr.
__global__ void gather_h_kernel(const __half* __restrict__ hg,
                                const int* __restrict__ gs,
                                const int* __restrict__ noff,
                                const float* __restrict__ earr,
                                float* __restrict__ out, int N) {
    int wid  = (blockIdx.x * blockDim.x + threadIdx.x) >> 6;
    int lane = threadIdx.x & 63;
    if (wid >= N) return;

    int beg = noff[wid];
    int end = noff[wid + 1];

    float a0 = 0.f, a1 = 0.f, a2 = 0.f, a3 = 0.f;
    float a4 = 0.f, a5 = 0.f, a6 = 0.f, a7 = 0.f;
    int j = beg;
    for (; j + 7 < end; j += 8) {
        int s0 = gs[j];     int s1 = gs[j + 1];
        int s2 = gs[j + 2]; int s3 = gs[j + 3];
        int s4 = gs[j + 4]; int s5 = gs[j + 5];
        int s6 = gs[j + 6]; int s7 = gs[j + 7];
        a0 += __half2float(hg[(size_t)s0 * 64 + lane]);
        a1 += __half2float(hg[(size_t)s1 * 64 + lane]);
        a2 += __half2float(hg[(size_t)s2 * 64 + lane]);
        a3 += __half2float(hg[(size_t)s3 * 64 + lane]);
        a4 += __half2float(hg[(size_t)s4 * 64 + lane]);
        a5 += __half2float(hg[(size_t)s5 * 64 + lane]);
        a6 += __half2float(hg[(size_t)s6 * 64 + lane]);
        a7 += __half2float(hg[(size_t)s7 * 64 + lane]);
    }
    for (; j + 3 < end; j += 4) {
        int s0 = gs[j];     int s1 = gs[j + 1];
        int s2 = gs[j + 2]; int s3 = gs[j + 3];
        a0 += __half2float(hg[(size_t)s0 * 64 + lane]);
        a1 += __half2float(hg[(size_t)s1 * 64 + lane]);
        a2 += __half2float(hg[(size_t)s2 * 64 + lane]);
        a3 += __half2float(hg[(size_t)s3 * 64 + lane]);
    }
    for (; j < end; ++j) {
        a0 += __half2float(hg[(size_t)gs[j] * 64 + lane]);
    }
    out[(size_t)wid * 65 + lane] = ((a0 + a1) + (a2 + a3)) + ((a4 + a5) + (a6 + a7));
    if (lane == 0) out[(size_t)wid * 65 + 64] = earr[wid];
}

// ---------------------- fallback (always correct) --------------------------

__global__ void atomic_fallback_kernel(const float* __restrict__ gemb,
                                       const float* __restrict__ efeat,
                                       const int* __restrict__ src,
                                       const int* __restrict__ dst,
                                       float* __restrict__ out, int E) {
    int eidx = blockIdx.x * 4 + (threadIdx.x >> 6);
    int lane = threadIdx.x & 63;
    if (eidx >= E) return;
    int s = src[eidx];
    int d = dst[eidx];
    float v = gemb[(size_t)s * 64 + lane];
    atomicAdd(&out[(size_t)d * 65 + lane], v);
    if (lane == 0) atomicAdd(&out[(size_t)d * 65 + 64], efeat[eidx]);
}

// ---------------------------------------------------------------------------

extern "C" void kernel_launch(void* const* d_in, const int* in_sizes, int n_in,
                              void* d_out, int out_size, void* d_ws, size_t ws_size,
                              hipStream_t stream) {
    const float* gemb  = (const float*)d_in[0];   // [N, 64]
    const float* efeat = (const float*)d_in[1];   // [E]
    const int*   src   = (const int*)d_in[2];     // [E]
    const int*   dst   = (const int*)d_in[3];     // [E]
    float*       out   = (float*)d_out;           // [N, 65]

    const int N  = in_sizes[0] / 64;
    const int E  = in_sizes[1];
    const int NB = (N + BNODES - 1) >> NB_SHIFT;

    auto aln = [](size_t x) { return (x + 63) & ~(size_t)63; };
    size_t off_counts = 0;                                    // [MAXNB] + earr: one memset
    size_t off_earr   = off_counts + (size_t)MAXNB * 4;
    size_t off_goff   = aln(off_earr + (size_t)N * 4);
    size_t off_gcur   = aln(off_goff + (size_t)(NB + 1) * 4);
    size_t off_noff   = aln(off_gcur + (size_t)NB * 4);
    size_t off_gkey   = aln(off_noff + (size_t)(N + 1) * 4);
    size_t off_gsrc2  = aln(off_gkey + (size_t)E * 4);
    size_t off_hg     = aln(off_gsrc2 + (size_t)E * 4);
    size_t needed     = off_hg + (size_t)N * 64 * 2;

    if (N > (1 << SRC_BITS) || NB > MAXNB || ws_size < needed) {
        hipMemsetAsync(d_out, 0, (size_t)out_size * sizeof(float), stream);
        int blocks = (E + 3) / 4;
        atomic_fallback_kernel<<<blocks, 256, 0, stream>>>(gemb, efeat, src, dst, out, E);
        return;
    }

    char*   ws     = (char*)d_ws;
    int*    counts = (int*)(ws + off_counts);
    float*  earr   = (float*)(ws + off_earr);
    int*    goff   = (int*)(ws + off_goff);
    int*    gcur   = (int*)(ws + off_gcur);
    int*    noff   = (int*)(ws + off_noff);
    int*    gkey   = (int*)(ws + off_gkey);
    int*    gsrc2  = (int*)(ws + off_gsrc2);
    __half* hg     = (__half*)(ws + off_hg);

    // single memset covers counts + earr (adjacent)
    hipMemsetAsync(counts, 0, (size_t)MAXNB * 4 + (size_t)N * 4, stream);

    int n_emb    = N * 64;
    int c_blocks = (n_emb + BIN_T * 8 - 1) / (BIN_T * 8);
    int h_blocks = (E + BIN_S - 1) / BIN_S;
    convhist_kernel<<<c_blocks + h_blocks, BIN_T, 0, stream>>>(
        gemb, hg, n_emb, c_blocks, dst, efeat, counts, earr, E, NB);

    scan_kernel<<<1, 512, 0, stream>>>(counts, goff, gcur, noff, NB, N);
    bin_kernel<<<h_blocks, BIN_T, 0, stream>>>(src, dst, gcur, gkey, E);
    bsort_kernel<<<NB, 512, 0, stream>>>(gkey, goff, gsrc2, noff, N);

    int g_blocks = (N + 3) / 4;
    gather_h_kernel<<<g_blocks, 256, 0, stream>>>(hg, gsrc2, noff, earr, out, N);
}

// Round 14
// 100.244 us; speedup vs baseline: 1.6385x; 1.6385x over previous
//
#include <hip/hip_runtime.h>
#include <hip/hip_fp16.h>

// ---------------------------------------------------------------------------
// Round-14: hybrid of r10 (proven 110us skeleton, ef rides through bin,
// esum in bsort LDS) and r13's slim prep (256-node buckets, 4B keys,
// shfl scans).
//   memset(counts) ;
//   convhist (fp32->fp16 table conv + 391-bucket hist; NO global atomics) ;
//   scan (1 block, shfl: bucket offsets; writes goff[NB], noff[N]) ;
//   bin (stage key+ef SoA in LDS, coalesced flush into bucket runs) ;
//   bsort (bucket-local counting sort; node-sorted 4B srcs + per-node
//          offsets; esum in LDS -> writes out[:,64]) ;
//   gather (r10-proven: 1 wave/node, 8-deep unroll, fp16 rows, linear store).
// Key: (dst & 255) << 17 | src   (needs N <= 2^17).
// ---------------------------------------------------------------------------

#define NB_SHIFT 8
#define BNODES   256          // nodes per bucket
#define SRC_BITS 17
#define SRC_MASK ((1 << SRC_BITS) - 1)
#define BIN_S    4096         // edges per bin/hist block
#define BIN_T    512
#define MAXNB    512

// Fused: blocks [0, c_blocks) convert the table fp32->fp16; the rest
// histogram dst into bucket counts (LDS-aggregated).
__global__ __launch_bounds__(BIN_T) void convhist_kernel(const float* __restrict__ g,
                                                         __half* __restrict__ h,
                                                         int n_emb, int c_blocks,
                                                         const int* __restrict__ dst,
                                                         int* __restrict__ counts,
                                                         int E, int NB) {
    __shared__ int cnt[MAXNB];
    int t = threadIdx.x;

    if (blockIdx.x < c_blocks) {
        int i = (blockIdx.x * BIN_T + t) * 8;
        if (i + 7 < n_emb) {
            float4 a = *(const float4*)(g + i);
            float4 b = *(const float4*)(g + i + 4);
            __half2 h0 = __floats2half2_rn(a.x, a.y);
            __half2 h1 = __floats2half2_rn(a.z, a.w);
            __half2 h2 = __floats2half2_rn(b.x, b.y);
            __half2 h3 = __floats2half2_rn(b.z, b.w);
            int4 o;
            o.x = *(int*)&h0; o.y = *(int*)&h1; o.z = *(int*)&h2; o.w = *(int*)&h3;
            *(int4*)(h + i) = o;
        } else {
            for (int k = i; k < n_emb; ++k) h[k] = __float2half(g[k]);
        }
        return;
    }

    int hb = blockIdx.x - c_blocks;
    cnt[t] = 0;
    __syncthreads();
    int e0 = hb * BIN_S + t * 8;
    if (e0 + 7 < E) {
        int4 a = *(const int4*)(dst + e0);
        int4 b = *(const int4*)(dst + e0 + 4);
        atomicAdd(&cnt[a.x >> NB_SHIFT], 1);
        atomicAdd(&cnt[a.y >> NB_SHIFT], 1);
        atomicAdd(&cnt[a.z >> NB_SHIFT], 1);
        atomicAdd(&cnt[a.w >> NB_SHIFT], 1);
        atomicAdd(&cnt[b.x >> NB_SHIFT], 1);
        atomicAdd(&cnt[b.y >> NB_SHIFT], 1);
        atomicAdd(&cnt[b.z >> NB_SHIFT], 1);
        atomicAdd(&cnt[b.w >> NB_SHIFT], 1);
    } else {
        for (int k = e0; k < E; ++k) atomicAdd(&cnt[dst[k] >> NB_SHIFT], 1);
    }
    __syncthreads();
    if (t < NB && cnt[t]) atomicAdd(&counts[t], cnt[t]);
}

// Exclusive scan over NB (<=512) counters; one block, 512 threads, shfl.
// Writes goff, gcur, goff[NB]=E, noff[N]=E.
__global__ __launch_bounds__(512) void scan_kernel(const int* __restrict__ counts,
                                                   int* __restrict__ goff,
                                                   int* __restrict__ gcur,
                                                   int* __restrict__ noff,
                                                   int NB, int N) {
    __shared__ int wsum[8];
    __shared__ int wbase[8];
    int t    = threadIdx.x;
    int lane = t & 63;
    int wv   = t >> 6;
    int v    = (t < NB) ? counts[t] : 0;
    int incl = v;
#pragma unroll
    for (int o = 1; o < 64; o <<= 1) {
        int u = __shfl_up(incl, o);
        if (lane >= o) incl += u;
    }
    if (lane == 63) wsum[wv] = incl;
    __syncthreads();
    if (t < 8) {
        int s = wsum[t];
        int inc = s;
#pragma unroll
        for (int o = 1; o < 8; o <<= 1) {
            int u = __shfl_up(inc, o);
            if (t >= o) inc += u;
        }
        wbase[t] = inc - s;
    }
    __syncthreads();
    int ex = wbase[wv] + (incl - v);
    if (t < NB) { goff[t] = ex; gcur[t] = ex; }
    if (t == 511) {
        int total = wbase[7] + incl;   // counts above NB are zero
        goff[NB] = total;
        noff[N]  = total;
    }
}

// bin: local histogram+rank (512 counters, 1/thread), shfl scans, stage
// key+ef SoA in LDS, coalesced flush into bucket runs.
__global__ __launch_bounds__(BIN_T) void bin_kernel(const int* __restrict__ src,
                                                    const float* __restrict__ ef,
                                                    const int* __restrict__ dst,
                                                    int* __restrict__ gcur,
                                                    int* __restrict__ gkey,
                                                    float* __restrict__ gef, int E) {
    __shared__ int cnt[MAXNB];              // 2 KB
    __shared__ int lbase[MAXNB];            // 2 KB
    __shared__ int wsum[8];
    __shared__ int wbase[8];
    __shared__ int skey[BIN_S];             // 16 KB
    __shared__ float sef[BIN_S];            // 16 KB
    __shared__ unsigned short sbuck[BIN_S]; // 8 KB   (total ~44 KB)

    const int t    = threadIdx.x;
    const int lane = t & 63;
    const int wv   = t >> 6;

    cnt[t] = 0;
    __syncthreads();

    int e0 = blockIdx.x * BIN_S + t * 8;
    int dv[8], sv[8], bk[8], rk[8];
    float ev[8];

    if (e0 + 7 < E) {
        *(int4*)&dv[0]   = *(const int4*)(dst + e0);
        *(int4*)&dv[4]   = *(const int4*)(dst + e0 + 4);
        *(int4*)&sv[0]   = *(const int4*)(src + e0);
        *(int4*)&sv[4]   = *(const int4*)(src + e0 + 4);
        *(float4*)&ev[0] = *(const float4*)(ef + e0);
        *(float4*)&ev[4] = *(const float4*)(ef + e0 + 4);
#pragma unroll
        for (int k = 0; k < 8; ++k) {
            bk[k] = dv[k] >> NB_SHIFT;
            rk[k] = atomicAdd(&cnt[bk[k]], 1);
        }
    } else {
#pragma unroll
        for (int k = 0; k < 8; ++k) {
            if (e0 + k < E) {
                dv[k] = dst[e0 + k];
                sv[k] = src[e0 + k];
                ev[k] = ef[e0 + k];
                bk[k] = dv[k] >> NB_SHIFT;
                rk[k] = atomicAdd(&cnt[bk[k]], 1);
            } else {
                bk[k] = -1;
            }
        }
    }
    __syncthreads();

    // exclusive scan of cnt[0..511], 1/thread: wave shfl scan + cross-wave
    int c = cnt[t];
    int incl = c;
#pragma unroll
    for (int o = 1; o < 64; o <<= 1) {
        int u = __shfl_up(incl, o);
        if (lane >= o) incl += u;
    }
    if (lane == 63) wsum[wv] = incl;
    __syncthreads();
    if (t < 8) {
        int s = wsum[t];
        int inc = s;
#pragma unroll
        for (int o = 1; o < 8; o <<= 1) {
            int u = __shfl_up(inc, o);
            if (t >= o) inc += u;
        }
        wbase[t] = inc - s;
    }
    __syncthreads();
    int lb = wbase[wv] + (incl - c);
    lbase[t] = lb;
    __syncthreads();

    // stage ranked payloads (SoA)
#pragma unroll
    for (int k = 0; k < 8; ++k) {
        if (bk[k] >= 0) {
            int pos = lbase[bk[k]] + rk[k];
            skey[pos]  = ((dv[k] & (BNODES - 1)) << SRC_BITS) | sv[k];
            sef[pos]   = ev[k];
            sbuck[pos] = (unsigned short)bk[k];
        }
    }
    // reserve; cnt[b] becomes (global_base - local_base)
    cnt[t] = (c ? atomicAdd(&gcur[t], c) : 0) - lb;
    __syncthreads();

    // coalesced flush (two streams, same scatter pattern)
    int s_total = min(BIN_S, E - blockIdx.x * BIN_S);
    for (int i = t; i < s_total; i += BIN_T) {
        int p = cnt[sbuck[i]] + i;
        gkey[p] = skey[i];
        gef[p]  = sef[i];
    }
}

// Bucket-local counting sort: one block per 256-node bucket, two passes over
// the L2-resident window. Emits node-sorted 4B srcs + per-node offsets;
// accumulates efeat per node in LDS and writes out[:,64].
__global__ __launch_bounds__(512) void bsort_kernel(const int* __restrict__ gkey,
                                                    const float* __restrict__ gef,
                                                    const int* __restrict__ goff,
                                                    int* __restrict__ gsrc2,
                                                    int* __restrict__ noff,
                                                    float* __restrict__ out,
                                                    int N) {
    __shared__ int   cnt[BNODES];
    __shared__ int   cur[BNODES];
    __shared__ float esum[BNODES];

    const int t  = threadIdx.x;
    const int b  = blockIdx.x;
    const int lo = goff[b];
    const int hi = goff[b + 1];

    if (t < BNODES) { cnt[t] = 0; esum[t] = 0.f; }
    __syncthreads();

    // pass 1: per-node histogram (keys only)
    for (int i = lo + t; i < hi; i += 512)
        atomicAdd(&cnt[gkey[i] >> SRC_BITS], 1);
    __syncthreads();

    // wave-0 shfl exclusive scan of 256 counters (4/lane)
    if (t < 64) {
        int c0 = cnt[4 * t], c1 = cnt[4 * t + 1], c2 = cnt[4 * t + 2], c3 = cnt[4 * t + 3];
        int ts = c0 + c1 + c2 + c3;
        int inc = ts;
#pragma unroll
        for (int o = 1; o < 64; o <<= 1) {
            int u = __shfl_up(inc, o);
            if (t >= o) inc += u;
        }
        int ex = inc - ts;
        int b0 = lo + ex;
        int b1 = b0 + c0;
        int b2 = b1 + c1;
        int b3 = b2 + c2;
        cur[4 * t]     = b0;
        cur[4 * t + 1] = b1;
        cur[4 * t + 2] = b2;
        cur[4 * t + 3] = b3;
        int node = b * BNODES + 4 * t;
        if (node     < N) noff[node]     = b0;
        if (node + 1 < N) noff[node + 1] = b1;
        if (node + 2 < N) noff[node + 2] = b2;
        if (node + 3 < N) noff[node + 3] = b3;
    }
    __syncthreads();

    // pass 2: place node-sorted srcs; accumulate efeat per node (LDS)
    for (int i = lo + t; i < hi; i += 512) {
        int k = gkey[i];
        int r = k >> SRC_BITS;
        int pos = atomicAdd(&cur[r], 1);
        gsrc2[pos] = k & SRC_MASK;
        atomicAdd(&esum[r], gef[i]);
    }
    __syncthreads();

    // efeat column
    if (t < BNODES) {
        int node = b * BNODES + t;
        if (node < N) out[(size_t)node * 65 + 64] = esum[t];
    }
}

// Gather: one wave per node, lane = feature, fp16 rows, 8-way unroll.
// (r10-proven: 49.5us, 67% occupancy.)
__global__ void gather_h_kernel(const __half* __restrict__ hg,
                                const int* __restrict__ gs,
                                const int* __restrict__ noff,
                                float* __restrict__ out, int N) {
    int wid  = (blockIdx.x * blockDim.x + threadIdx.x) >> 6;
    int lane = threadIdx.x & 63;
    if (wid >= N) return;

    int beg = noff[wid];
    int end = noff[wid + 1];

    float a0 = 0.f, a1 = 0.f, a2 = 0.f, a3 = 0.f;
    float a4 = 0.f, a5 = 0.f, a6 = 0.f, a7 = 0.f;
    int j = beg;
    for (; j + 7 < end; j += 8) {
        int s0 = gs[j];     int s1 = gs[j + 1];
        int s2 = gs[j + 2]; int s3 = gs[j + 3];
        int s4 = gs[j + 4]; int s5 = gs[j + 5];
        int s6 = gs[j + 6]; int s7 = gs[j + 7];
        a0 += __half2float(hg[(size_t)s0 * 64 + lane]);
        a1 += __half2float(hg[(size_t)s1 * 64 + lane]);
        a2 += __half2float(hg[(size_t)s2 * 64 + lane]);
        a3 += __half2float(hg[(size_t)s3 * 64 + lane]);
        a4 += __half2float(hg[(size_t)s4 * 64 + lane]);
        a5 += __half2float(hg[(size_t)s5 * 64 + lane]);
        a6 += __half2float(hg[(size_t)s6 * 64 + lane]);
        a7 += __half2float(hg[(size_t)s7 * 64 + lane]);
    }
    for (; j + 3 < end; j += 4) {
        int s0 = gs[j];     int s1 = gs[j + 1];
        int s2 = gs[j + 2]; int s3 = gs[j + 3];
        a0 += __half2float(hg[(size_t)s0 * 64 + lane]);
        a1 += __half2float(hg[(size_t)s1 * 64 + lane]);
        a2 += __half2float(hg[(size_t)s2 * 64 + lane]);
        a3 += __half2float(hg[(size_t)s3 * 64 + lane]);
    }
    for (; j < end; ++j) {
        a0 += __half2float(hg[(size_t)gs[j] * 64 + lane]);
    }
    out[(size_t)wid * 65 + lane] = ((a0 + a1) + (a2 + a3)) + ((a4 + a5) + (a6 + a7));
}

// ---------------------- fallback (always correct) --------------------------

__global__ void atomic_fallback_kernel(const float* __restrict__ gemb,
                                       const float* __restrict__ efeat,
                                       const int* __restrict__ src,
                                       const int* __restrict__ dst,
                                       float* __restrict__ out, int E) {
    int eidx = blockIdx.x * 4 + (threadIdx.x >> 6);
    int lane = threadIdx.x & 63;
    if (eidx >= E) return;
    int s = src[eidx];
    int d = dst[eidx];
    float v = gemb[(size_t)s * 64 + lane];
    atomicAdd(&out[(size_t)d * 65 + lane], v);
    if (lane == 0) atomicAdd(&out[(size_t)d * 65 + 64], efeat[eidx]);
}

// ---------------------------------------------------------------------------

extern "C" void kernel_launch(void* const* d_in, const int* in_sizes, int n_in,
                              void* d_out, int out_size, void* d_ws, size_t ws_size,
                              hipStream_t stream) {
    const float* gemb  = (const float*)d_in[0];   // [N, 64]
    const float* efeat = (const float*)d_in[1];   // [E]
    const int*   src   = (const int*)d_in[2];     // [E]
    const int*   dst   = (const int*)d_in[3];     // [E]
    float*       out   = (float*)d_out;           // [N, 65]

    const int N  = in_sizes[0] / 64;
    const int E  = in_sizes[1];
    const int NB = (N + BNODES - 1) >> NB_SHIFT;

    auto aln = [](size_t x) { return (x + 63) & ~(size_t)63; };
    size_t off_counts = 0;                                    // [MAXNB]
    size_t off_goff   = aln(off_counts + (size_t)MAXNB * 4);
    size_t off_gcur   = aln(off_goff + (size_t)(NB + 1) * 4);
    size_t off_noff   = aln(off_gcur + (size_t)NB * 4);
    size_t off_gkey   = aln(off_noff + (size_t)(N + 1) * 4);
    size_t off_gef    = aln(off_gkey + (size_t)E * 4);
    size_t off_gsrc2  = aln(off_gef  + (size_t)E * 4);
    size_t off_hg     = aln(off_gsrc2 + (size_t)E * 4);
    size_t needed     = off_hg + (size_t)N * 64 * 2;

    if (N > (1 << SRC_BITS) || NB > MAXNB || ws_size < needed) {
        hipMemsetAsync(d_out, 0, (size_t)out_size * sizeof(float), stream);
        int blocks = (E + 3) / 4;
        atomic_fallback_kernel<<<blocks, 256, 0, stream>>>(gemb, efeat, src, dst, out, E);
        return;
    }

    char*   ws     = (char*)d_ws;
    int*    counts = (int*)(ws + off_counts);
    int*    goff   = (int*)(ws + off_goff);
    int*    gcur   = (int*)(ws + off_gcur);
    int*    noff   = (int*)(ws + off_noff);
    int*    gkey   = (int*)(ws + off_gkey);
    float*  gef    = (float*)(ws + off_gef);
    int*    gsrc2  = (int*)(ws + off_gsrc2);
    __half* hg     = (__half*)(ws + off_hg);

    hipMemsetAsync(counts, 0, (size_t)MAXNB * 4, stream);

    int n_emb    = N * 64;
    int c_blocks = (n_emb + BIN_T * 8 - 1) / (BIN_T * 8);
    int h_blocks = (E + BIN_S - 1) / BIN_S;
    convhist_kernel<<<c_blocks + h_blocks, BIN_T, 0, stream>>>(
        gemb, hg, n_emb, c_blocks, dst, counts, E, NB);

    scan_kernel<<<1, 512, 0, stream>>>(counts, goff, gcur, noff, NB, N);
    bin_kernel<<<h_blocks, BIN_T, 0, stream>>>(src, efeat, dst, gcur, gkey, gef, E);
    bsort_kernel<<<NB, 512, 0, stream>>>(gkey, gef, goff, gsrc2, noff, out, N);

    int g_blocks = (N + 3) / 4;
    gather_h_kernel<<<g_blocks, 256, 0, stream>>>(hg, gsrc2, noff, out, N);
}